// Round 1
// baseline (287.226 us; speedup 1.0000x reference)
//
#include <hip/hip_runtime.h>
#include <stdint.h>

#define CIN 256
#define COUT 256
#define RANK 64
#define H_ 112
#define W_ 112
#define HW_ (112*112)

typedef short bf16x8 __attribute__((ext_vector_type(8)));   // 8 bf16 = 4 VGPRs
typedef float f32x4 __attribute__((ext_vector_type(4)));

// round-to-nearest-even fp32 -> bf16, packed pair
__device__ __forceinline__ unsigned rne2(float a, float b){
  unsigned ua = __builtin_bit_cast(unsigned, a);
  unsigned ub = __builtin_bit_cast(unsigned, b);
  ua += 0x7FFFu + ((ua >> 16) & 1u);
  ub += 0x7FFFu + ((ub >> 16) & 1u);
  return (ua >> 16) | (ub & 0xFFFF0000u);
}
__device__ __forceinline__ unsigned short rne1(float a){
  unsigned ua = __builtin_bit_cast(unsigned, a);
  ua += 0x7FFFu + ((ua >> 16) & 1u);
  return (unsigned short)(ua >> 16);
}

// ---- K0a: w_sum[o][i] = sum_k w_head[k][o][i] ----
__global__ __launch_bounds__(256) void k_wsum(const float* __restrict__ wh,
                                              float* __restrict__ wsum){
  int o = blockIdx.x, i = threadIdx.x;
  float s = 0.f;
  for (int k = 0; k < RANK; ++k) s += wh[(k*COUT + o)*CIN + i];
  wsum[o*CIN + i] = s;
}

// ---- K0b: w_eff[dh][r][i] = sum_o w_body[r][o][dh] * w_sum[o][i]  (bf16) ----
__global__ __launch_bounds__(256) void k_weff(const float* __restrict__ wb,
                                              const float* __restrict__ wsum,
                                              unsigned short* __restrict__ weff){
  int bid = blockIdx.x;              // dh*64 + r
  int dh = bid >> 6, r = bid & 63;
  int i = threadIdx.x;
  float s = 0.f;
  for (int o = 0; o < COUT; ++o)
    s += wb[(r*COUT + o)*3 + dh] * wsum[o*CIN + i];
  weff[bid*CIN + i] = rne1(s);
}

// ---- K0c: wtp[o][dw][r] = w_tail[o][r][dw]  (bf16) ----
__global__ __launch_bounds__(256) void k_wtp(const float* __restrict__ wt,
                                             unsigned short* __restrict__ wtp){
  int o = blockIdx.x, t = threadIdx.x;
  if (t < 192){
    int dw = t >> 6, r = t & 63;
    wtp[o*192 + t] = rne1(wt[(o*RANK + r)*3 + dw]);
  }
}

// ---- K1: y2[b][h][w][r] (bf16) = body-conv(x, w_eff) ----
// Grid: 16 * 28 blocks, 256 threads (4 waves). Block = (b, 4 h-rows).
// Wave wid computes full 64 r x 112 w for h = h0+wid. K = (i,dh) = 768.
__global__ __launch_bounds__(256,2) void k_body(const float* __restrict__ x,
                                                const unsigned short* __restrict__ weff,
                                                unsigned short* __restrict__ y2){
  // [6 rows][112 w][32 i] bf16, row stride padded to 36 ushorts (72 B)
  __shared__ alignas(16) unsigned short lds[6*112*36];
  const int tid  = threadIdx.x;
  const int wid  = tid >> 6, lane = tid & 63, g = lane >> 4, l15 = lane & 15;
  const int bb   = blockIdx.x / 28, hb = blockIdx.x % 28;
  const int h0   = hb*4;
  const float* xb = x + bb*CIN*HW_;

  f32x4 acc[4][7];
  #pragma unroll
  for (int a = 0; a < 4; ++a)
    #pragma unroll
    for (int b = 0; b < 7; ++b) acc[a][b] = (f32x4){0.f,0.f,0.f,0.f};

  for (int i0 = 0; i0 < 8; ++i0){
    // stage x rows h0-1..h0+4, channels i0*32..+31, fp32 -> bf16 transposed
    for (int j = 0; j < 21; ++j){
      int s   = tid + 256*j;         // 5376 strips: (row, i4, w)
      int w   = s % 112;
      int t2  = s / 112;             // 0..47
      int i4  = t2 & 7, row = t2 >> 3;
      int grow = h0 - 1 + row;
      unsigned lo = 0, hi = 0;
      if (grow >= 0 && grow < H_){
        const float* p = xb + (i0*32 + i4*4)*HW_ + grow*W_ + w;
        float v0 = p[0], v1 = p[HW_], v2 = p[2*HW_], v3 = p[3*HW_];
        lo = rne2(v0, v1); hi = rne2(v2, v3);
      }
      uint2 st; st.x = lo; st.y = hi;
      *(uint2*)&lds[(row*112 + w)*36 + i4*4] = st;
    }
    __syncthreads();
    #pragma unroll
    for (int dh = 0; dh < 3; ++dh){
      bf16x8 af[4];
      const int abase = (dh*64 + l15)*CIN + i0*32 + g*8;
      #pragma unroll
      for (int rt = 0; rt < 4; ++rt)
        af[rt] = *(const bf16x8*)(weff + abase + rt*16*CIN);
      const int ldsrow = wid + dh;
      const unsigned short* qb = lds + (ldsrow*112 + l15)*36 + g*8;
      #pragma unroll
      for (int wt = 0; wt < 7; ++wt){
        uint2 b0 = *(const uint2*)(qb + wt*576);
        uint2 b1 = *(const uint2*)(qb + wt*576 + 4);
        uint4 bb4; bb4.x = b0.x; bb4.y = b0.y; bb4.z = b1.x; bb4.w = b1.y;
        bf16x8 bf = __builtin_bit_cast(bf16x8, bb4);
        #pragma unroll
        for (int rt = 0; rt < 4; ++rt)
          acc[rt][wt] = __builtin_amdgcn_mfma_f32_16x16x32_bf16(af[rt], bf, acc[rt][wt], 0, 0, 0);
      }
    }
    __syncthreads();
  }
  // epilogue: y2[b][h][w][r] bf16, r-contiguous b64 stores
  const int h = h0 + wid;
  unsigned short* yb = y2 + ((bb*H_ + h)*W_)*64;
  #pragma unroll
  for (int wt = 0; wt < 7; ++wt){
    #pragma unroll
    for (int rt = 0; rt < 4; ++rt){
      unsigned lo = rne2(acc[rt][wt][0], acc[rt][wt][1]);
      unsigned hi = rne2(acc[rt][wt][2], acc[rt][wt][3]);
      uint2 st; st.x = lo; st.y = hi;
      *(uint2*)(yb + (wt*16 + l15)*64 + rt*16 + g*4) = st;
    }
  }
}

// ---- K2: out[b][o][h][w] = bias[o] + tail-conv(y2, wtp) ----
// Grid: 16 * 112 blocks, 256 threads. Block = (b, h). Wave wid owns o-quarter.
__global__ __launch_bounds__(256,2) void k_tail(const unsigned short* __restrict__ y2,
                                                const unsigned short* __restrict__ wtp,
                                                const float* __restrict__ bias,
                                                float* __restrict__ out){
  // [114 w'][64 r] bf16, row stride padded to 72 ushorts (144 B); w' = w+1 (halo)
  __shared__ alignas(16) unsigned short ldsY[114*72];
  const int tid = threadIdx.x;
  const int wid = tid >> 6, lane = tid & 63, g = lane >> 4, l15 = lane & 15;
  const int bb  = blockIdx.x / 112, h = blockIdx.x % 112;
  const unsigned short* yb = y2 + ((bb*H_ + h)*W_)*64;

  for (int idx = tid; idx < 114*8; idx += 256){
    int w = idx >> 3, c = idx & 7;
    uint4 v = {0,0,0,0};
    if (w >= 1 && w <= 112) v = *(const uint4*)(yb + (w-1)*64 + c*8);
    *(uint4*)&ldsY[w*72 + c*8] = v;
  }
  __syncthreads();

  f32x4 acc[4][7];
  #pragma unroll
  for (int a = 0; a < 4; ++a)
    #pragma unroll
    for (int b = 0; b < 7; ++b) acc[a][b] = (f32x4){0.f,0.f,0.f,0.f};

  #pragma unroll
  for (int s = 0; s < 6; ++s){       // k-step: dw = s>>1, r-half = s&1
    bf16x8 af[4];
    const int abase = (wid*64 + l15)*192 + s*32 + g*8;
    #pragma unroll
    for (int rt = 0; rt < 4; ++rt)
      af[rt] = *(const bf16x8*)(wtp + abase + rt*16*192);
    const unsigned short* qb = ldsY + (l15 + (s>>1))*72 + (s&1)*32 + g*8;
    #pragma unroll
    for (int wt = 0; wt < 7; ++wt){
      bf16x8 bf = *(const bf16x8*)(qb + wt*16*72);   // ds_read_b128, 16B-aligned
      #pragma unroll
      for (int rt = 0; rt < 4; ++rt)
        acc[rt][wt] = __builtin_amdgcn_mfma_f32_16x16x32_bf16(af[rt], bf, acc[rt][wt], 0, 0, 0);
    }
  }

  float bv[4][4];
  #pragma unroll
  for (int rt = 0; rt < 4; ++rt)
    #pragma unroll
    for (int ii = 0; ii < 4; ++ii)
      bv[rt][ii] = bias[wid*64 + rt*16 + g*4 + ii];

  float* ob = out + ((size_t)bb*COUT)*HW_ + h*W_;
  #pragma unroll
  for (int rt = 0; rt < 4; ++rt)
    #pragma unroll
    for (int wt = 0; wt < 7; ++wt)
      #pragma unroll
      for (int ii = 0; ii < 4; ++ii)
        ob[(size_t)(wid*64 + rt*16 + g*4 + ii)*HW_ + wt*16 + l15] = acc[rt][wt][ii] + bv[rt][ii];
}

extern "C" void kernel_launch(void* const* d_in, const int* in_sizes, int n_in,
                              void* d_out, int out_size, void* d_ws, size_t ws_size,
                              hipStream_t stream) {
  const float* x      = (const float*)d_in[0];
  const float* w_head = (const float*)d_in[1];
  const float* w_body = (const float*)d_in[2];
  const float* w_tail = (const float*)d_in[3];
  const float* b_tail = (const float*)d_in[4];
  float* out = (float*)d_out;

  char* ws = (char*)d_ws;
  unsigned short* y2   = (unsigned short*)ws;                 // 25,690,112 B
  float*          wsum = (float*)(ws + 25690112);             //    262,144 B
  unsigned short* weff = (unsigned short*)(ws + 25952256);    //     98,304 B
  unsigned short* wtp  = (unsigned short*)(ws + 26050560);    //     98,304 B

  k_wsum<<<256, 256, 0, stream>>>(w_head, wsum);
  k_weff<<<192, 256, 0, stream>>>(w_body, wsum, weff);
  k_wtp <<<256, 256, 0, stream>>>(w_tail, wtp);
  k_body<<<16*28, 256, 0, stream>>>(x, weff, y2);
  k_tail<<<16*112, 256, 0, stream>>>(y2, wtp, b_tail, out);
}

// Round 2
// 197.926 us; speedup vs baseline: 1.4512x; 1.4512x over previous
//
#include <hip/hip_runtime.h>
#include <stdint.h>

#define CIN 256
#define COUT 256
#define RANK 64
#define H_ 112
#define W_ 112
#define HW_ (112*112)

typedef unsigned short ushort_t;
typedef short bf16x8 __attribute__((ext_vector_type(8)));   // 8 bf16 = 4 VGPRs
typedef float f32x4 __attribute__((ext_vector_type(4)));

// round-to-nearest-even fp32 -> bf16, packed pair
__device__ __forceinline__ unsigned rne2(float a, float b){
  unsigned ua = __builtin_bit_cast(unsigned, a);
  unsigned ub = __builtin_bit_cast(unsigned, b);
  ua += 0x7FFFu + ((ua >> 16) & 1u);
  ub += 0x7FFFu + ((ub >> 16) & 1u);
  return (ua >> 16) | (ub & 0xFFFF0000u);
}
__device__ __forceinline__ unsigned short rne1(float a){
  unsigned ua = __builtin_bit_cast(unsigned, a);
  ua += 0x7FFFu + ((ua >> 16) & 1u);
  return (unsigned short)(ua >> 16);
}

// ---- K0a: w_sum[o][i] = sum_k w_head[k][o][i] ----
__global__ __launch_bounds__(256) void k_wsum(const float* __restrict__ wh,
                                              float* __restrict__ wsum){
  int o = blockIdx.x, i = threadIdx.x;
  float s = 0.f;
  for (int k = 0; k < RANK; ++k) s += wh[(k*COUT + o)*CIN + i];
  wsum[o*CIN + i] = s;
}

// ---- K0b: w_eff[dh][r][i] = sum_o w_body[r][o][dh] * w_sum[o][i]  (bf16) ----
__global__ __launch_bounds__(256) void k_weff(const float* __restrict__ wb,
                                              const float* __restrict__ wsum,
                                              unsigned short* __restrict__ weff){
  int bid = blockIdx.x;              // dh*64 + r
  int dh = bid >> 6, r = bid & 63;
  int i = threadIdx.x;
  float s = 0.f;
  for (int o = 0; o < COUT; ++o)
    s += wb[(r*COUT + o)*3 + dh] * wsum[o*CIN + i];
  weff[bid*CIN + i] = rne1(s);
}

// ---- K0c: wtp[o][dw][r] = w_tail[o][r][dw]  (bf16) ----
__global__ __launch_bounds__(256) void k_wtp(const float* __restrict__ wt,
                                             unsigned short* __restrict__ wtp){
  int o = blockIdx.x, t = threadIdx.x;
  if (t < 192){
    int dw = t >> 6, r = t & 63;
    wtp[o*192 + t] = rne1(wt[(o*RANK + r)*3 + dw]);
  }
}

// ---- K_xt: x fp32 NCHW -> x_t bf16 [b][hh=114][i0=8][g=4][w=112][c=8] ----
// hh = h+1; rows hh=0 and hh=113 are zero pads. Layout is chosen so k_body
// can stage one (row,i0) chunk (7168 B contiguous) with 7 linear
// global_load_lds ops and ds_read B-fragments conflict-free.
__global__ __launch_bounds__(256) void k_xt(const float* __restrict__ x,
                                            unsigned short* __restrict__ xt){
  __shared__ float ldsf[64*120];
  const int tid = threadIdx.x;
  const int bb = blockIdx.x / 114, hh = blockIdx.x % 114;
  const int h = hh - 1;
  unsigned short* dst = xt + ((size_t)(bb*114 + hh))*28672;

  if (h < 0 || h >= H_){
    uint4 z = {0,0,0,0};
    #pragma unroll
    for (int j = 0; j < 14; ++j)
      *(uint4*)(dst + (tid + 256*j)*8) = z;
    return;
  }

  for (int i0p = 0; i0p < 4; ++i0p){   // 64 channels per pass
    // stage: 1792 float4 (64 ch x 28 quads), coalesced
    int c = tid / 28, wq = tid % 28;
    #pragma unroll
    for (int j = 0; j < 7; ++j){
      const float4 v = *(const float4*)(x + ((size_t)(bb*CIN + i0p*64 + c))*HW_ + h*W_ + wq*4);
      *(float4*)&ldsf[c*120 + wq*4] = v;
      // idx += 256: c += 9, wq += 4 (256 = 9*28 + 4)
      wq += 4; c += 9; if (wq >= 28){ wq -= 28; c += 1; }
    }
    __syncthreads();
    // write: 896 chunks of 16B; chunk = g8*112 + w; out offset contiguous
    for (int chunk = tid; chunk < 896; chunk += 256){
      int g8 = chunk / 112, w = chunk % 112;
      const float* src = &ldsf[(g8*8)*120 + w];
      uint4 st;
      st.x = rne2(src[0],     src[120]);
      st.y = rne2(src[240],   src[360]);
      st.z = rne2(src[480],   src[600]);
      st.w = rne2(src[720],   src[840]);
      *(uint4*)(dst + (size_t)(i0p*896 + chunk)*8) = st;
    }
    __syncthreads();
  }
}

// ---- K1: y2[b][h][w][r] (bf16) = body-conv(x_t, w_eff) ----
// Grid: 16*56 blocks (b, h-pair), 256 threads / 4 waves.
// Wave wid: hloc = wid>>1, rhalf = wid&1 -> 1 h-row x 32 r x 112 w.
// Double-buffered LDS, async global_load_lds staging (wave wid stages row wid).
__global__ __launch_bounds__(256,2) void k_body(const unsigned short* __restrict__ xt,
                                                const unsigned short* __restrict__ weff,
                                                unsigned short* __restrict__ y2){
  __shared__ alignas(16) unsigned short lds[2*4*3584];   // 57344 B
  const int tid  = threadIdx.x;
  const int wid  = tid >> 6, lane = tid & 63, g = lane >> 4, l15 = lane & 15;
  const int bb   = blockIdx.x / 56, hb = blockIdx.x % 56;
  const int h0   = hb*2;
  const int hloc = wid >> 1, rhalf = wid & 1;

  f32x4 acc[2][7];
  #pragma unroll
  for (int a = 0; a < 2; ++a)
    #pragma unroll
    for (int b = 0; b < 7; ++b) acc[a][b] = (f32x4){0.f,0.f,0.f,0.f};

  // staging: wave wid loads global row hh = h0 + wid (covers h0-1 .. h0+2)
  const unsigned short* rowbase = xt + ((size_t)(bb*114 + h0 + wid)*8)*3584;

  auto stage = [&](unsigned short* dstbuf, int i0){
    const unsigned short* src = rowbase + (size_t)i0*3584 + lane*8;
    unsigned short* dstb = dstbuf + wid*3584;
    #pragma unroll
    for (int k = 0; k < 7; ++k)
      __builtin_amdgcn_global_load_lds(
        (const __attribute__((address_space(1))) void*)(src + k*512),
        (__attribute__((address_space(3))) void*)(dstb + k*512), 16, 0, 0);
  };

  auto compute = [&](const unsigned short* buf, int i0){
    #pragma unroll
    for (int dh = 0; dh < 3; ++dh){
      const int row = hloc + dh;
      const unsigned short* ab = weff + (size_t)(dh*64 + rhalf*32 + l15)*CIN + i0*32 + g*8;
      bf16x8 af0 = *(const bf16x8*)(ab);
      bf16x8 af1 = *(const bf16x8*)(ab + 16*CIN);
      const unsigned short* qb = buf + row*3584 + g*896 + l15*8;
      #pragma unroll
      for (int wt = 0; wt < 7; ++wt){
        bf16x8 bfv = *(const bf16x8*)(qb + wt*128);
        acc[0][wt] = __builtin_amdgcn_mfma_f32_16x16x32_bf16(af0, bfv, acc[0][wt], 0, 0, 0);
        acc[1][wt] = __builtin_amdgcn_mfma_f32_16x16x32_bf16(af1, bfv, acc[1][wt], 0, 0, 0);
      }
    }
  };

  unsigned short* cur = lds;
  unsigned short* nxt = lds + 14336;
  stage(cur, 0);
  __syncthreads();
  for (int t = 0; t < 8; ++t){
    if (t < 7) stage(nxt, t+1);
    compute(cur, t);
    __syncthreads();                 // drains vmcnt (prefetch) + lgkmcnt
    unsigned short* tmp = cur; cur = nxt; nxt = tmp;
  }

  // epilogue: y2[b][h][w][64 r], r-contiguous b64 stores
  const int h = h0 + hloc;
  unsigned short* yb = y2 + ((size_t)(bb*H_ + h)*W_)*64;
  #pragma unroll
  for (int wt = 0; wt < 7; ++wt){
    #pragma unroll
    for (int rt = 0; rt < 2; ++rt){
      unsigned lo = rne2(acc[rt][wt][0], acc[rt][wt][1]);
      unsigned hi = rne2(acc[rt][wt][2], acc[rt][wt][3]);
      uint2 st; st.x = lo; st.y = hi;
      *(uint2*)(yb + (wt*16 + l15)*64 + rhalf*32 + rt*16 + g*4) = st;
    }
  }
}

// ---- K2: out[b][o][h][w] = bias[o] + tail-conv(y2, wtp) ----
__global__ __launch_bounds__(256,2) void k_tail(const unsigned short* __restrict__ y2,
                                                const unsigned short* __restrict__ wtp,
                                                const float* __restrict__ bias,
                                                float* __restrict__ out){
  __shared__ alignas(16) unsigned short ldsY[114*72];
  const int tid = threadIdx.x;
  const int wid = tid >> 6, lane = tid & 63, g = lane >> 4, l15 = lane & 15;
  const int bb  = blockIdx.x / 112, h = blockIdx.x % 112;
  const unsigned short* yb = y2 + ((size_t)(bb*H_ + h)*W_)*64;

  for (int idx = tid; idx < 114*8; idx += 256){
    int w = idx >> 3, c = idx & 7;
    uint4 v = {0,0,0,0};
    if (w >= 1 && w <= 112) v = *(const uint4*)(yb + (w-1)*64 + c*8);
    *(uint4*)&ldsY[w*72 + c*8] = v;
  }
  __syncthreads();

  f32x4 acc[4][7];
  #pragma unroll
  for (int a = 0; a < 4; ++a)
    #pragma unroll
    for (int b = 0; b < 7; ++b) acc[a][b] = (f32x4){0.f,0.f,0.f,0.f};

  #pragma unroll
  for (int s = 0; s < 6; ++s){       // k-step: dw = s>>1, r-half = s&1
    bf16x8 af[4];
    const int abase = (wid*64 + l15)*192 + s*32 + g*8;
    #pragma unroll
    for (int rt = 0; rt < 4; ++rt)
      af[rt] = *(const bf16x8*)(wtp + abase + rt*16*192);
    const unsigned short* qb = ldsY + (l15 + (s>>1))*72 + (s&1)*32 + g*8;
    #pragma unroll
    for (int wt = 0; wt < 7; ++wt){
      bf16x8 bf = *(const bf16x8*)(qb + wt*16*72);
      #pragma unroll
      for (int rt = 0; rt < 4; ++rt)
        acc[rt][wt] = __builtin_amdgcn_mfma_f32_16x16x32_bf16(af[rt], bf, acc[rt][wt], 0, 0, 0);
    }
  }

  float bv[4][4];
  #pragma unroll
  for (int rt = 0; rt < 4; ++rt)
    #pragma unroll
    for (int ii = 0; ii < 4; ++ii)
      bv[rt][ii] = bias[wid*64 + rt*16 + g*4 + ii];

  float* ob = out + ((size_t)bb*COUT)*HW_ + h*W_;
  #pragma unroll
  for (int rt = 0; rt < 4; ++rt)
    #pragma unroll
    for (int wt = 0; wt < 7; ++wt)
      #pragma unroll
      for (int ii = 0; ii < 4; ++ii)
        ob[(size_t)(wid*64 + rt*16 + g*4 + ii)*HW_ + wt*16 + l15] = acc[rt][wt][ii] + bv[rt][ii];
}

extern "C" void kernel_launch(void* const* d_in, const int* in_sizes, int n_in,
                              void* d_out, int out_size, void* d_ws, size_t ws_size,
                              hipStream_t stream) {
  const float* x      = (const float*)d_in[0];
  const float* w_head = (const float*)d_in[1];
  const float* w_body = (const float*)d_in[2];
  const float* w_tail = (const float*)d_in[3];
  const float* b_tail = (const float*)d_in[4];
  float* out = (float*)d_out;

  char* ws = (char*)d_ws;
  unsigned short* y2   = (unsigned short*)ws;                 // 25,690,112 B
  float*          wsum = (float*)(ws + 25690112);             //    262,144 B
  unsigned short* weff = (unsigned short*)(ws + 25952256);    //     98,304 B
  unsigned short* wtp  = (unsigned short*)(ws + 26050560);    //     98,304 B

  // x_t lives in d_out (104.5 MB needed, 205 MB available); k_tail
  // overwrites d_out with the final output after k_body consumed x_t.
  unsigned short* xt = (unsigned short*)d_out;

  k_wsum<<<256, 256, 0, stream>>>(w_head, wsum);
  k_weff<<<192, 256, 0, stream>>>(w_body, wsum, weff);
  k_wtp <<<256, 256, 0, stream>>>(w_tail, wtp);
  k_xt  <<<16*114, 256, 0, stream>>>(x, xt);
  k_body<<<16*56, 256, 0, stream>>>(xt, weff, y2);
  k_tail<<<16*112, 256, 0, stream>>>(y2, wtp, b_tail, out);
}

// Round 4
// 181.591 us; speedup vs baseline: 1.5817x; 1.0900x over previous
//
#include <hip/hip_runtime.h>
#include <stdint.h>

#define CIN 256
#define COUT 256
#define RANK 64
#define H_ 112
#define W_ 112
#define HW_ (112*112)

typedef short bf16x8 __attribute__((ext_vector_type(8)));   // 8 bf16 = 4 VGPRs
typedef float f32x4 __attribute__((ext_vector_type(4)));

// round-to-nearest-even fp32 -> bf16, packed pair
__device__ __forceinline__ unsigned rne2(float a, float b){
  unsigned ua = __builtin_bit_cast(unsigned, a);
  unsigned ub = __builtin_bit_cast(unsigned, b);
  ua += 0x7FFFu + ((ua >> 16) & 1u);
  ub += 0x7FFFu + ((ub >> 16) & 1u);
  return (ua >> 16) | (ub & 0xFFFF0000u);
}
__device__ __forceinline__ unsigned short rne1(float a){
  unsigned ua = __builtin_bit_cast(unsigned, a);
  ua += 0x7FFFu + ((ua >> 16) & 1u);
  return (unsigned short)(ua >> 16);
}

// ---- K_pre1: blocks [0, nb*114): x NCHW fp32 -> xt bf16 [lb][hh=114][i0=8][g=4][w=112][c=8]
//              blocks [nb*114, +256): w_sum[o][i] = sum_k w_head[k][o][i]  (chunk 0 only)
__global__ __launch_bounds__(256) void k_pre1(const float* __restrict__ x,
                                              unsigned short* __restrict__ xt,
                                              const float* __restrict__ wh,
                                              float* __restrict__ wsum,
                                              int base_b, int nb){
  __shared__ float ldsf[64*120];
  const int tid = threadIdx.x;
  if (blockIdx.x >= (unsigned)(nb*114)){
    int o = blockIdx.x - nb*114;
    float s = 0.f;
    for (int k = 0; k < RANK; ++k) s += wh[(k*COUT + o)*CIN + tid];
    wsum[o*CIN + tid] = s;
    return;
  }
  const int lb = blockIdx.x / 114, hh = blockIdx.x % 114;
  const int bb = base_b + lb;
  const int h = hh - 1;
  unsigned short* dst = xt + ((size_t)(lb*114 + hh))*28672;

  if (h < 0 || h >= H_){
    uint4 z = {0,0,0,0};
    #pragma unroll
    for (int j = 0; j < 14; ++j)
      *(uint4*)(dst + (tid + 256*j)*8) = z;
    return;
  }

  for (int i0p = 0; i0p < 4; ++i0p){   // 64 channels per pass
    int c = tid / 28, wq = tid % 28;
    #pragma unroll
    for (int j = 0; j < 7; ++j){
      const float4 v = *(const float4*)(x + ((size_t)(bb*CIN + i0p*64 + c))*HW_ + h*W_ + wq*4);
      *(float4*)&ldsf[c*120 + wq*4] = v;
      wq += 4; c += 9; if (wq >= 28){ wq -= 28; c += 1; }
    }
    __syncthreads();
    for (int ck = tid; ck < 896; ck += 256){
      int g8 = ck / 112, w = ck % 112;
      const float* src = &ldsf[(g8*8)*120 + w];
      uint4 st;
      st.x = rne2(src[0],     src[120]);
      st.y = rne2(src[240],   src[360]);
      st.z = rne2(src[480],   src[600]);
      st.w = rne2(src[720],   src[840]);
      *(uint4*)(dst + (size_t)(i0p*896 + ck)*8) = st;
    }
    __syncthreads();
  }
}

// ---- K_pre2: blocks [0,192): w_eff[dh][r][i] (bf16); blocks [192,448): wtp[o][dw][r] (bf16)
__global__ __launch_bounds__(256) void k_pre2(const float* __restrict__ wb,
                                              const float* __restrict__ wsum,
                                              unsigned short* __restrict__ weff,
                                              const float* __restrict__ wt,
                                              unsigned short* __restrict__ wtp){
  const int tid = threadIdx.x;
  if (blockIdx.x < 192){
    int bid = blockIdx.x;            // dh*64 + r
    int dh = bid >> 6, r = bid & 63;
    float s = 0.f;
    for (int o = 0; o < COUT; ++o)
      s += wb[(r*COUT + o)*3 + dh] * wsum[o*CIN + tid];
    weff[bid*CIN + tid] = rne1(s);
  } else {
    int o = blockIdx.x - 192;
    if (tid < 192){
      int dw = tid >> 6, r = tid & 63;
      wtp[o*192 + tid] = rne1(wt[(o*RANK + r)*3 + dw]);
    }
  }
}

// ---- K_fused: body GEMM -> LDS y2 -> tail GEMM -> out (fp32, NCHW) ----
// Grid: nb*56 blocks (lb, h-pair), 256 threads / 4 waves.
// Phase A: wave wid: hloc=wid>>1, rhalf=wid&1 -> 1 h-row x 32 r x 112 w.
// Phase C: wave wid: hloc=wid>>1, rhalf=wid&1 -> 2 passes of 64 o.
__global__ __launch_bounds__(256,2) void k_fused(const unsigned short* __restrict__ xt,
                                                 const unsigned short* __restrict__ weff,
                                                 const unsigned short* __restrict__ wtp,
                                                 const float* __restrict__ bias,
                                                 float* __restrict__ out,
                                                 int base_b){
  __shared__ alignas(16) unsigned short lds[28672];  // 57344 B: stage dbuf, then y2 buf
  const int tid  = threadIdx.x;
  const int wid  = tid >> 6, lane = tid & 63, g = lane >> 4, l15 = lane & 15;
  const int lb   = blockIdx.x / 56, hb = blockIdx.x % 56;
  const int bb   = base_b + lb;
  const int h0   = hb*2;
  const int hloc = wid >> 1, rhalf = wid & 1;

  // ---- phase A: body GEMM ----
  f32x4 acc[2][7];
  #pragma unroll
  for (int a = 0; a < 2; ++a)
    #pragma unroll
    for (int b = 0; b < 7; ++b) acc[a][b] = (f32x4){0.f,0.f,0.f,0.f};

  const unsigned short* rowbase = xt + ((size_t)(lb*114 + h0 + wid)*8)*3584;

  auto stage = [&](unsigned short* dstbuf, int i0){
    const unsigned short* src = rowbase + (size_t)i0*3584 + lane*8;
    unsigned short* dstb = dstbuf + wid*3584;
    #pragma unroll
    for (int k = 0; k < 7; ++k)
      __builtin_amdgcn_global_load_lds(
        (const __attribute__((address_space(1))) void*)(src + k*512),
        (__attribute__((address_space(3))) void*)(dstb + k*512), 16, 0, 0);
  };

  auto compute = [&](const unsigned short* buf, int i0){
    #pragma unroll
    for (int dh = 0; dh < 3; ++dh){
      const int row = hloc + dh;
      const unsigned short* ab = weff + (size_t)(dh*64 + rhalf*32 + l15)*CIN + i0*32 + g*8;
      bf16x8 af0 = *(const bf16x8*)(ab);
      bf16x8 af1 = *(const bf16x8*)(ab + 16*CIN);
      const unsigned short* qb = buf + row*3584 + g*896 + l15*8;
      #pragma unroll
      for (int wt = 0; wt < 7; ++wt){
        bf16x8 bfv = *(const bf16x8*)(qb + wt*128);
        acc[0][wt] = __builtin_amdgcn_mfma_f32_16x16x32_bf16(af0, bfv, acc[0][wt], 0, 0, 0);
        acc[1][wt] = __builtin_amdgcn_mfma_f32_16x16x32_bf16(af1, bfv, acc[1][wt], 0, 0, 0);
      }
    }
  };

  unsigned short* cur = lds;
  unsigned short* nxt = lds + 14336;
  stage(cur, 0);
  __syncthreads();
  for (int t = 0; t < 8; ++t){
    if (t < 7) stage(nxt, t+1);
    compute(cur, t);
    __syncthreads();
    unsigned short* tmp = cur; cur = nxt; nxt = tmp;
  }

  // ---- phase B: acc -> LDS y2 buffer [2 h][114 w'][72 pad] (bf16), w' = w+1 ----
  unsigned short* y2b = lds;
  if (tid < 32){
    int hh = tid >> 4, wsel = (tid >> 3) & 1, rq = tid & 7;
    *(uint4*)(y2b + hh*8208 + (wsel ? 113 : 0)*72 + rq*8) = (uint4){0,0,0,0};
  }
  #pragma unroll
  for (int wt = 0; wt < 7; ++wt){
    #pragma unroll
    for (int rt = 0; rt < 2; ++rt){
      unsigned lo = rne2(acc[rt][wt][0], acc[rt][wt][1]);
      unsigned hi = rne2(acc[rt][wt][2], acc[rt][wt][3]);
      uint2 st; st.x = lo; st.y = hi;
      *(uint2*)(y2b + hloc*8208 + (wt*16 + l15 + 1)*72 + rhalf*32 + rt*16 + g*4) = st;
    }
  }
  __syncthreads();

  // ---- phase C: tail GEMM, 2 passes of 64 o per wave ----
  const int h = h0 + hloc;
  #pragma unroll
  for (int opass = 0; opass < 2; ++opass){
    const int obase = rhalf*128 + opass*64;
    f32x4 a2[4][7];
    #pragma unroll
    for (int a = 0; a < 4; ++a)
      #pragma unroll
      for (int b = 0; b < 7; ++b) a2[a][b] = (f32x4){0.f,0.f,0.f,0.f};

    #pragma unroll
    for (int s = 0; s < 6; ++s){       // k-step: dw = s>>1, r-half = s&1
      bf16x8 af[4];
      const unsigned short* ab = wtp + (size_t)(obase + l15)*192 + s*32 + g*8;
      #pragma unroll
      for (int rt = 0; rt < 4; ++rt)
        af[rt] = *(const bf16x8*)(ab + rt*16*192);
      const unsigned short* qb = y2b + hloc*8208 + (l15 + (s >> 1))*72 + (s & 1)*32 + g*8;
      #pragma unroll
      for (int wt = 0; wt < 7; ++wt){
        bf16x8 bv = *(const bf16x8*)(qb + wt*16*72);
        #pragma unroll
        for (int rt = 0; rt < 4; ++rt)
          a2[rt][wt] = __builtin_amdgcn_mfma_f32_16x16x32_bf16(af[rt], bv, a2[rt][wt], 0, 0, 0);
      }
    }

    float* ob = out + ((size_t)(bb*COUT) + obase)*HW_ + h*W_;
    #pragma unroll
    for (int rt = 0; rt < 4; ++rt){
      #pragma unroll
      for (int ii = 0; ii < 4; ++ii){
        float bvv = bias[obase + rt*16 + g*4 + ii];
        #pragma unroll
        for (int wt = 0; wt < 7; ++wt)
          ob[(size_t)(rt*16 + g*4 + ii)*HW_ + wt*16 + l15] = a2[rt][wt][ii] + bvv;
      }
    }
  }
}

extern "C" void kernel_launch(void* const* d_in, const int* in_sizes, int n_in,
                              void* d_out, int out_size, void* d_ws, size_t ws_size,
                              hipStream_t stream) {
  const float* x      = (const float*)d_in[0];
  const float* w_head = (const float*)d_in[1];
  const float* w_body = (const float*)d_in[2];
  const float* w_tail = (const float*)d_in[3];
  const float* b_tail = (const float*)d_in[4];
  float* out = (float*)d_out;
  char* ws = (char*)d_ws;

  // ws layout: wsum fp32 [256][256] @0 (262144 B); weff bf16 @262144 (98304 B);
  // wtp bf16 @360448 (98304 B); xt chunk buffer @458752.
  float*          wsum = (float*)ws;
  unsigned short* weff = (unsigned short*)(ws + 262144);
  unsigned short* wtp  = (unsigned short*)(ws + 360448);
  unsigned short* xt   = (unsigned short*)(ws + 458752);

  const size_t XT_ROW_BYTES = 57344;                     // 28672 ushorts * 2
  const size_t XT_PER_B     = 114 * XT_ROW_BYTES;        // 6,537,216 B
  size_t avail = (ws_size > 458752) ? ws_size - 458752 : 0;
  int chunk_b = (int)(avail / XT_PER_B);
  if (chunk_b > 16) chunk_b = 16;
  if (chunk_b < 1)  chunk_b = 1;                         // ws proven >= 26.1 MB, so >= 3
  int nchunks = (16 + chunk_b - 1) / chunk_b;

  int base = 0;
  for (int c = 0; c < nchunks; ++c){
    int remaining = 16 - base;
    int nb = (remaining + (nchunks - c) - 1) / (nchunks - c);   // balanced split
    k_pre1<<<nb*114 + (c == 0 ? 256 : 0), 256, 0, stream>>>(x, xt, w_head, wsum, base, nb);
    if (c == 0)
      k_pre2<<<448, 256, 0, stream>>>(w_body, wsum, weff, w_tail, wtp);
    k_fused<<<nb*56, 256, 0, stream>>>(xt, weff, wtp, b_tail, out, base);
    base += nb;
  }
}